// Round 1
// baseline (2791.077 us; speedup 1.0000x reference)
//
#include <hip/hip_runtime.h>
#include <hip/hip_bf16.h>
#include <math.h>

// Problem constants (fixed shapes from setup_inputs)
#define B_    2
#define N_    2048
#define D_    1024
#define H_    16
#define ENC_  8
#define HD_   64
#define EPS_  1e-5f
#define M_    (B_ * N_)        // 4096 rows for all GEMMs

// ---------------------------------------------------------------------------
// Tiled fp32 GEMM: C[M,Nn] = A[M,K] @ Bm[K,Nn]
// A has row stride lda and column offset aoff (for the sliced dec projection).
// 64x64 block tile, BK=16, 256 threads, 4x4 microtile per thread.
// ---------------------------------------------------------------------------
__global__ __launch_bounds__(256) void gemm_f32(
    const float* __restrict__ A, const float* __restrict__ Bm,
    float* __restrict__ C, int M, int Nn, int K, int lda, int aoff)
{
    __shared__ float As[16][64];   // [k][m]
    __shared__ float Bs[16][64];   // [k][n]

    const int bm  = blockIdx.y * 64;
    const int bn  = blockIdx.x * 64;
    const int tid = threadIdx.x;
    const int tx  = tid & 15;      // 0..15 -> col group
    const int ty  = tid >> 4;      // 0..15 -> row group

    float acc[4][4] = {};

    for (int k0 = 0; k0 < K; k0 += 16) {
        // Stage A tile (64 rows x 16 k), transposed into As[k][m]
        {
            const int row = tid >> 2;            // 0..63
            const int kc  = (tid & 3) << 2;      // 0,4,8,12
            float4 av = *(const float4*)&A[(size_t)(bm + row) * lda + aoff + k0 + kc];
            As[kc + 0][row] = av.x;
            As[kc + 1][row] = av.y;
            As[kc + 2][row] = av.z;
            As[kc + 3][row] = av.w;
            // Stage B tile (16 k x 64 n), coalesced float4
            const int brow = tid >> 4;           // 0..15
            const int bc   = (tid & 15) << 2;    // 0..60
            *(float4*)&Bs[brow][bc] =
                *(const float4*)&Bm[(size_t)(k0 + brow) * Nn + bn + bc];
        }
        __syncthreads();

        #pragma unroll
        for (int kk = 0; kk < 16; ++kk) {
            float4 av = *(const float4*)&As[kk][ty * 4];
            float4 bv = *(const float4*)&Bs[kk][tx * 4];
            float a[4] = {av.x, av.y, av.z, av.w};
            float b[4] = {bv.x, bv.y, bv.z, bv.w};
            #pragma unroll
            for (int ii = 0; ii < 4; ++ii)
                #pragma unroll
                for (int jj = 0; jj < 4; ++jj)
                    acc[ii][jj] = fmaf(a[ii], b[jj], acc[ii][jj]);
        }
        __syncthreads();
    }

    #pragma unroll
    for (int ii = 0; ii < 4; ++ii) {
        float4 r = make_float4(acc[ii][0], acc[ii][1], acc[ii][2], acc[ii][3]);
        *(float4*)&C[(size_t)(bm + ty * 4 + ii) * Nn + bn + tx * 4] = r;
    }
}

// ---------------------------------------------------------------------------
// Fused RoPE + RMSNorm applied in-place to q and k.
// One 64-lane wave per (b, n, h) row; block = 256 threads = 4 rows.
// ---------------------------------------------------------------------------
__global__ __launch_bounds__(256) void rope_rms(
    float* __restrict__ q, float* __restrict__ k,
    const float* __restrict__ cs, const float* __restrict__ sn)
{
    const int row  = blockIdx.x * 4 + (threadIdx.x >> 6);  // (b*N + n)*H + h
    const int lane = threadIdx.x & 63;
    const int n    = (row >> 4) & (N_ - 1);                // row / H % N  (H=16)
    const int p    = lane >> 1;                            // pair index 0..31

    const float c = cs[n * (HD_ / 2) + p];
    const float s = sn[n * (HD_ / 2) + p];
    const size_t base = (size_t)row * HD_ + lane;
    const bool odd = (lane & 1);

    // ---- q ----
    {
        float val = q[base];
        float partner = __shfl_xor(val, 1, 64);
        // even lane holds re (x[2p]), odd lane holds im (x[2p+1])
        float r = odd ? fmaf(partner, s, val * c)   // re*s + im*c
                      : (val * c - partner * s);    // re*c - im*s
        float ss = r * r;
        #pragma unroll
        for (int off = 1; off < 64; off <<= 1) ss += __shfl_xor(ss, off, 64);
        q[base] = r * rsqrtf(ss * (1.0f / 64.0f) + EPS_);
    }
    // ---- k ----
    {
        float val = k[base];
        float partner = __shfl_xor(val, 1, 64);
        float r = odd ? fmaf(partner, s, val * c)
                      : (val * c - partner * s);
        float ss = r * r;
        #pragma unroll
        for (int off = 1; off < 64; off <<= 1) ss += __shfl_xor(ss, off, 64);
        k[base] = r * rsqrtf(ss * (1.0f / 64.0f) + EPS_);
    }
}

// ---------------------------------------------------------------------------
// Flash-style attention, fp32. One thread = one query row i of one (b,h).
// Scores bounded in [-8,8] (rms-normed q,k: |q|=|k|=8, scale=1/8), so a fixed
// softmax max of 8 is safe -> no online-max rescaling, branch-free inner loop.
// Block = 256 threads (256 query rows); K/V staged in 64-row LDS tiles.
// ---------------------------------------------------------------------------
__global__ __launch_bounds__(256) void attn(
    const float* __restrict__ q, const float* __restrict__ k,
    const float* __restrict__ v, float* __restrict__ o)
{
    __shared__ float Ks[64][68];   // +4 pad breaks staging-write bank conflicts
    __shared__ float Vs[64][68];

    const int bh = blockIdx.x;           // 0..31
    const int b  = bh >> 4;              // H=16
    const int h  = bh & 15;
    const int i  = blockIdx.y * 256 + threadIdx.x;
    const bool enc = (h < ENC_);

    const float* qrow = q + ((size_t)(b * N_ + i) * H_ + h) * HD_;
    float4 qreg[16];
    #pragma unroll
    for (int p = 0; p < 16; ++p) qreg[p] = *(const float4*)&qrow[p * 4];

    float4 oa[16];
    #pragma unroll
    for (int p = 0; p < 16; ++p) oa[p] = make_float4(0.f, 0.f, 0.f, 0.f);
    float lsum = 0.f;

    const int jmax   = enc ? (N_ - 1) : i;                        // last allowed j
    const int blkmax = enc ? (N_ - 1) : (blockIdx.y * 256 + 255); // block-wide bound
    const int ntiles = (blkmax + 64) >> 6;

    // exp(s*0.125 - 8) = exp2(s*kscale + koff)
    const float kscale = 0.125f * 1.4426950408889634f;
    const float koff   = -8.0f * 1.4426950408889634f;

    for (int t = 0; t < ntiles; ++t) {
        const int j0 = t << 6;
        __syncthreads();
        {
            const int jr = threadIdx.x >> 2;           // 0..63 tile row
            const int c0 = (threadIdx.x & 3) << 4;     // 0,16,32,48
            const float* krow = k + ((size_t)(b * N_ + j0 + jr) * H_ + h) * HD_ + c0;
            const float* vrow = v + ((size_t)(b * N_ + j0 + jr) * H_ + h) * HD_ + c0;
            #pragma unroll
            for (int u = 0; u < 4; ++u) {
                *(float4*)&Ks[jr][c0 + u * 4] = *(const float4*)&krow[u * 4];
                *(float4*)&Vs[jr][c0 + u * 4] = *(const float4*)&vrow[u * 4];
            }
        }
        __syncthreads();

        const int jend = min(64, jmax - j0 + 1);   // may be <= 0 (thread idles)
        for (int j = 0; j < jend; ++j) {
            float s = 0.f;
            #pragma unroll
            for (int p = 0; p < 16; ++p) {
                float4 kk = *(const float4*)&Ks[j][p * 4];
                s = fmaf(qreg[p].x, kk.x, s);
                s = fmaf(qreg[p].y, kk.y, s);
                s = fmaf(qreg[p].z, kk.z, s);
                s = fmaf(qreg[p].w, kk.w, s);
            }
            float pz = exp2f(fmaf(s, kscale, koff));
            lsum += pz;
            #pragma unroll
            for (int p = 0; p < 16; ++p) {
                float4 vv = *(const float4*)&Vs[j][p * 4];
                oa[p].x = fmaf(pz, vv.x, oa[p].x);
                oa[p].y = fmaf(pz, vv.y, oa[p].y);
                oa[p].z = fmaf(pz, vv.z, oa[p].z);
                oa[p].w = fmaf(pz, vv.w, oa[p].w);
            }
        }
    }

    const float inv = 1.0f / lsum;   // lsum >= exp(s_0 - 8) > 0 always
    float* orow = o + ((size_t)(b * N_ + i) * H_ + h) * HD_;
    #pragma unroll
    for (int p = 0; p < 16; ++p) {
        float4 r = make_float4(oa[p].x * inv, oa[p].y * inv,
                               oa[p].z * inv, oa[p].w * inv);
        *(float4*)&orow[p * 4] = r;
    }
}

// ---------------------------------------------------------------------------
extern "C" void kernel_launch(void* const* d_in, const int* in_sizes, int n_in,
                              void* d_out, int out_size, void* d_ws, size_t ws_size,
                              hipStream_t stream)
{
    const float* x   = (const float*)d_in[0];
    const float* cs  = (const float*)d_in[1];
    const float* sn  = (const float*)d_in[2];
    const float* Wq  = (const float*)d_in[3];
    const float* Wk  = (const float*)d_in[4];
    const float* Wv  = (const float*)d_in[5];
    const float* Woe = (const float*)d_in[6];
    const float* Wod = (const float*)d_in[7];
    // d_in[8]=heads(16), d_in[9]=encoder_heads(8): hardcoded above.

    float* enc_out = (float*)d_out;                      // (B,N,D)
    float* dec_out = enc_out + (size_t)M_ * D_;          // (B,N,D)

    float* qbuf = (float*)d_ws;                          // B*N*D fp32 = 16 MB
    float* kbuf = qbuf + (size_t)M_ * D_;
    float* vbuf = kbuf + (size_t)M_ * D_;
    float* obuf = vbuf + (size_t)M_ * D_;

    const dim3 gemmBlk(256);
    const dim3 gemmGrd(D_ / 64, M_ / 64);                // (16, 64)

    // QKV projections
    gemm_f32<<<gemmGrd, gemmBlk, 0, stream>>>(x, Wq, qbuf, M_, D_, D_, D_, 0);
    gemm_f32<<<gemmGrd, gemmBlk, 0, stream>>>(x, Wk, kbuf, M_, D_, D_, D_, 0);
    gemm_f32<<<gemmGrd, gemmBlk, 0, stream>>>(x, Wv, vbuf, M_, D_, D_, D_, 0);

    // RoPE + RMSNorm on q, k (in place)
    rope_rms<<<(B_ * N_ * H_) / 4, 256, 0, stream>>>(qbuf, kbuf, cs, sn);

    // Attention -> obuf (B,N,H,HD)
    attn<<<dim3(B_ * H_, N_ / 256), 256, 0, stream>>>(qbuf, kbuf, vbuf, obuf);

    // Output projections
    gemm_f32<<<gemmGrd, gemmBlk, 0, stream>>>(obuf, Woe, enc_out, M_, D_, D_, D_, 0);
    gemm_f32<<<gemmGrd, gemmBlk, 0, stream>>>(obuf, Wod, dec_out, M_, D_,
                                              (H_ - ENC_) * HD_, D_, ENC_ * HD_);
}

// Round 2
// 735.987 us; speedup vs baseline: 3.7923x; 3.7923x over previous
//
#include <hip/hip_runtime.h>
#include <hip/hip_bf16.h>
#include <math.h>

// Problem constants (fixed shapes from setup_inputs)
#define B_    2
#define N_    2048
#define D_    1024
#define H_    16
#define ENC_  8
#define HD_   64
#define EPS_  1e-5f
#define M_    (B_ * N_)        // 4096 rows for all GEMMs

typedef __bf16 bf16x8 __attribute__((ext_vector_type(8)));
typedef float  f32x4  __attribute__((ext_vector_type(4)));

// ---------------------------------------------------------------------------
// Tiled fp32 GEMM: C[M,Nn] = A[M,K] @ Bm[K,Nn]   (unchanged from R1)
// ---------------------------------------------------------------------------
__global__ __launch_bounds__(256) void gemm_f32(
    const float* __restrict__ A, const float* __restrict__ Bm,
    float* __restrict__ C, int M, int Nn, int K, int lda, int aoff)
{
    __shared__ float As[16][64];   // [k][m]
    __shared__ float Bs[16][64];   // [k][n]

    const int bm  = blockIdx.y * 64;
    const int bn  = blockIdx.x * 64;
    const int tid = threadIdx.x;
    const int tx  = tid & 15;
    const int ty  = tid >> 4;

    float acc[4][4] = {};

    for (int k0 = 0; k0 < K; k0 += 16) {
        {
            const int row = tid >> 2;
            const int kc  = (tid & 3) << 2;
            float4 av = *(const float4*)&A[(size_t)(bm + row) * lda + aoff + k0 + kc];
            As[kc + 0][row] = av.x;
            As[kc + 1][row] = av.y;
            As[kc + 2][row] = av.z;
            As[kc + 3][row] = av.w;
            const int brow = tid >> 4;
            const int bc   = (tid & 15) << 2;
            *(float4*)&Bs[brow][bc] =
                *(const float4*)&Bm[(size_t)(k0 + brow) * Nn + bn + bc];
        }
        __syncthreads();

        #pragma unroll
        for (int kk = 0; kk < 16; ++kk) {
            float4 av = *(const float4*)&As[kk][ty * 4];
            float4 bv = *(const float4*)&Bs[kk][tx * 4];
            float a[4] = {av.x, av.y, av.z, av.w};
            float b[4] = {bv.x, bv.y, bv.z, bv.w};
            #pragma unroll
            for (int ii = 0; ii < 4; ++ii)
                #pragma unroll
                for (int jj = 0; jj < 4; ++jj)
                    acc[ii][jj] = fmaf(a[ii], b[jj], acc[ii][jj]);
        }
        __syncthreads();
    }

    #pragma unroll
    for (int ii = 0; ii < 4; ++ii) {
        float4 r = make_float4(acc[ii][0], acc[ii][1], acc[ii][2], acc[ii][3]);
        *(float4*)&C[(size_t)(bm + ty * 4 + ii) * Nn + bn + tx * 4] = r;
    }
}

// ---------------------------------------------------------------------------
// Fused RoPE + RMSNorm; reads fp32 q,k (B,N,H,HD), writes bf16 head-major
// (B,H,N,HD) for the MFMA attention kernel. One wave per (b,n,h) row.
// ---------------------------------------------------------------------------
__global__ __launch_bounds__(256) void rope_rms_bf(
    const float* __restrict__ q, const float* __restrict__ k,
    const float* __restrict__ cs, const float* __restrict__ sn,
    __bf16* __restrict__ qbf, __bf16* __restrict__ kbf)
{
    const int row  = blockIdx.x * 4 + (threadIdx.x >> 6);  // (b*N + n)*H + h
    const int lane = threadIdx.x & 63;
    const int n    = (row >> 4) & (N_ - 1);
    const int b    = row >> 15;                            // / (N*H) = 2^15
    const int h    = row & 15;
    const int p    = lane >> 1;

    const float c = cs[n * (HD_ / 2) + p];
    const float s = sn[n * (HD_ / 2) + p];
    const size_t ibase = (size_t)row * HD_ + lane;
    const size_t obase = ((size_t)(b * H_ + h) * N_ + n) * HD_ + lane;
    const bool odd = (lane & 1);

    {
        float val = q[ibase];
        float partner = __shfl_xor(val, 1, 64);
        float r = odd ? fmaf(partner, s, val * c)
                      : (val * c - partner * s);
        float ss = r * r;
        #pragma unroll
        for (int off = 1; off < 64; off <<= 1) ss += __shfl_xor(ss, off, 64);
        qbf[obase] = (__bf16)(r * rsqrtf(ss * (1.0f / 64.0f) + EPS_));
    }
    {
        float val = k[ibase];
        float partner = __shfl_xor(val, 1, 64);
        float r = odd ? fmaf(partner, s, val * c)
                      : (val * c - partner * s);
        float ss = r * r;
        #pragma unroll
        for (int off = 1; off < 64; off <<= 1) ss += __shfl_xor(ss, off, 64);
        kbf[obase] = (__bf16)(r * rsqrtf(ss * (1.0f / 64.0f) + EPS_));
    }
}

// ---------------------------------------------------------------------------
// V convert + transpose: fp32 (B,N,H,HD) -> bf16 (B,H,HD,N).
// Block = one (b,h) x 64-seq tile, LDS transpose.
// ---------------------------------------------------------------------------
__global__ __launch_bounds__(256) void vconv(
    const float* __restrict__ v, __bf16* __restrict__ vt)
{
    __shared__ __bf16 tile[64][72];    // 144 B rows (16 B multiple)
    const int bh = blockIdx.y;
    const int b  = bh >> 4, h = bh & 15;
    const int n0 = blockIdx.x * 64;
    {
        const int nl = threadIdx.x >> 2;
        const int d0 = (threadIdx.x & 3) * 16;
        const float* src = v + ((size_t)((b * N_ + n0 + nl) * H_ + h)) * HD_ + d0;
        #pragma unroll
        for (int u = 0; u < 4; ++u) {
            float4 f = *(const float4*)&src[u * 4];
            tile[d0 + u * 4 + 0][nl] = (__bf16)f.x;
            tile[d0 + u * 4 + 1][nl] = (__bf16)f.y;
            tile[d0 + u * 4 + 2][nl] = (__bf16)f.z;
            tile[d0 + u * 4 + 3][nl] = (__bf16)f.w;
        }
    }
    __syncthreads();
    {
        const int dl = threadIdx.x >> 2;
        const int nc = (threadIdx.x & 3) * 16;
        __bf16* dst = vt + ((size_t)(bh * HD_ + dl)) * N_ + n0 + nc;
        *(bf16x8*)&dst[0] = *(const bf16x8*)&tile[dl][nc];
        *(bf16x8*)&dst[8] = *(const bf16x8*)&tile[dl][nc + 8];
    }
}

// ---------------------------------------------------------------------------
// MFMA flash attention (bf16 in, fp32 out). Per wave: 32 query rows (two
// 16-row MFMA tiles) of one (b,h); iterate 32-key tiles. Fixed softmax max
// of 8 (scores bounded: rms-normed q,k with |q|=|k|=8, scale 1/8).
// QK^T: mfma_f32_16x16x32_bf16, A=Q frag, B=K frag (both row=lane&15,
// dims (lane>>4)*8..+7). P exits in C-layout (col=lane&15, row=quad*4+r),
// round-trips through LDS into A-layout for PV. V pre-transposed so PV's
// B-operand loads are contiguous 16 B. No block-level sync anywhere ->
// waves fully independent (causal waves have divergent trip counts).
// ---------------------------------------------------------------------------
__global__ __launch_bounds__(256) void attn_mfma(
    const __bf16* __restrict__ qbf, const __bf16* __restrict__ kbf,
    const __bf16* __restrict__ vtbf, float* __restrict__ o)
{
    __shared__ __bf16 Plds[4][2][16][32];   // [wave][qtile][qrow][key]

    const int w    = threadIdx.x >> 6;
    const int lane = threadIdx.x & 63;
    const int lrow = lane & 15;
    const int quad = lane >> 4;

    const int bh = blockIdx.y;          // 0..31
    const int b  = bh >> 4, h = bh & 15;
    const bool enc = (h < ENC_);
    const int i0 = blockIdx.x * 128 + w * 32;   // wave's first query row

    const __bf16* qbase = qbf  + (size_t)bh * N_ * HD_;
    const __bf16* kbase = kbf  + (size_t)bh * N_ * HD_;
    const __bf16* vbase = vtbf + (size_t)bh * HD_ * N_;

    // Q fragments: [qtile][k-chunk(32 dims each)]
    bf16x8 qf[2][2];
    #pragma unroll
    for (int qt = 0; qt < 2; ++qt)
        #pragma unroll
        for (int kc = 0; kc < 2; ++kc)
            qf[qt][kc] = *(const bf16x8*)
                &qbase[(size_t)(i0 + qt * 16 + lrow) * HD_ + kc * 32 + quad * 8];

    const f32x4 zero = {0.f, 0.f, 0.f, 0.f};
    f32x4 oacc[2][4];                  // [qtile][16-dim chunk]
    #pragma unroll
    for (int qt = 0; qt < 2; ++qt)
        #pragma unroll
        for (int c = 0; c < 4; ++c) oacc[qt][c] = zero;
    float lsum[2][4] = {};

    const float KS = 0.125f * 1.4426950408889634f;   // log2e / 8
    const float KO = -8.0f  * 1.4426950408889634f;   // -8 * log2e

    const int jend = enc ? N_ : (i0 + 32);
    for (int j0 = 0; j0 < jend; j0 += 32) {
        // K fragments for the two 16-key tiles (dims split into 2 chunks)
        bf16x8 kf0a = *(const bf16x8*)&kbase[(size_t)(j0 + lrow) * HD_ + quad * 8];
        bf16x8 kf0b = *(const bf16x8*)&kbase[(size_t)(j0 + lrow) * HD_ + 32 + quad * 8];
        bf16x8 kf1a = *(const bf16x8*)&kbase[(size_t)(j0 + 16 + lrow) * HD_ + quad * 8];
        bf16x8 kf1b = *(const bf16x8*)&kbase[(size_t)(j0 + 16 + lrow) * HD_ + 32 + quad * 8];

        #pragma unroll
        for (int qt = 0; qt < 2; ++qt) {
            f32x4 s0 = zero, s1 = zero;
            s0 = __builtin_amdgcn_mfma_f32_16x16x32_bf16(qf[qt][0], kf0a, s0, 0, 0, 0);
            s0 = __builtin_amdgcn_mfma_f32_16x16x32_bf16(qf[qt][1], kf0b, s0, 0, 0, 0);
            s1 = __builtin_amdgcn_mfma_f32_16x16x32_bf16(qf[qt][0], kf1a, s1, 0, 0, 0);
            s1 = __builtin_amdgcn_mfma_f32_16x16x32_bf16(qf[qt][1], kf1b, s1, 0, 0, 0);
            #pragma unroll
            for (int r = 0; r < 4; ++r) {
                const int i  = i0 + qt * 16 + quad * 4 + r;
                const int jA = j0 + lrow;
                const int jB = j0 + 16 + lrow;
                float pA = (enc || jA <= i) ? exp2f(fmaf(s0[r], KS, KO)) : 0.f;
                float pB = (enc || jB <= i) ? exp2f(fmaf(s1[r], KS, KO)) : 0.f;
                lsum[qt][r] += pA + pB;
                Plds[w][qt][quad * 4 + r][lrow]      = (__bf16)pA;
                Plds[w][qt][quad * 4 + r][lrow + 16] = (__bf16)pB;
            }
        }

        // V fragments: 4 x 16-dim chunks, contiguous in key (transposed V)
        bf16x8 vf[4];
        #pragma unroll
        for (int c = 0; c < 4; ++c)
            vf[c] = *(const bf16x8*)&vbase[(size_t)(c * 16 + lrow) * N_ + j0 + quad * 8];

        #pragma unroll
        for (int qt = 0; qt < 2; ++qt) {
            bf16x8 pf = *(const bf16x8*)&Plds[w][qt][lrow][quad * 8];
            #pragma unroll
            for (int c = 0; c < 4; ++c)
                oacc[qt][c] = __builtin_amdgcn_mfma_f32_16x16x32_bf16(
                    pf, vf[c], oacc[qt][c], 0, 0, 0);
        }
    }

    // Row-sum reduction across the 16 lanes holding each row's columns
    #pragma unroll
    for (int qt = 0; qt < 2; ++qt)
        #pragma unroll
        for (int r = 0; r < 4; ++r) {
            float s = lsum[qt][r];
            s += __shfl_xor(s, 1, 64);
            s += __shfl_xor(s, 2, 64);
            s += __shfl_xor(s, 4, 64);
            s += __shfl_xor(s, 8, 64);
            lsum[qt][r] = 1.0f / s;
        }

    // Store O (fp32, B,N,H,HD): C-layout row=quad*4+r (query), col=lane&15 (dim)
    #pragma unroll
    for (int qt = 0; qt < 2; ++qt)
        #pragma unroll
        for (int c = 0; c < 4; ++c)
            #pragma unroll
            for (int r = 0; r < 4; ++r) {
                const int i = i0 + qt * 16 + quad * 4 + r;
                o[((size_t)(b * N_ + i) * H_ + h) * HD_ + c * 16 + lrow] =
                    oacc[qt][c][r] * lsum[qt][r];
            }
}

// ---------------------------------------------------------------------------
extern "C" void kernel_launch(void* const* d_in, const int* in_sizes, int n_in,
                              void* d_out, int out_size, void* d_ws, size_t ws_size,
                              hipStream_t stream)
{
    const float* x   = (const float*)d_in[0];
    const float* cs  = (const float*)d_in[1];
    const float* sn  = (const float*)d_in[2];
    const float* Wq  = (const float*)d_in[3];
    const float* Wk  = (const float*)d_in[4];
    const float* Wv  = (const float*)d_in[5];
    const float* Woe = (const float*)d_in[6];
    const float* Wod = (const float*)d_in[7];

    float* enc_out = (float*)d_out;
    float* dec_out = enc_out + (size_t)M_ * D_;

    // Workspace layout (64 MB total, with stream-ordered aliasing):
    //   [0,16M)   qbuf fp32   -> later reused as vtbf (bf16 V^T)
    //   [16,32M)  kbuf fp32   -> later reused as obuf (fp32 attn out)
    //   [32,48M)  vbuf fp32
    //   [48,56M)  qbf bf16 head-major
    //   [56,64M)  kbf bf16 head-major
    char* ws = (char*)d_ws;
    float*  qbuf = (float*)(ws + 0);
    float*  kbuf = (float*)(ws + (size_t)16 * 1024 * 1024);
    float*  vbuf = (float*)(ws + (size_t)32 * 1024 * 1024);
    __bf16* qbf  = (__bf16*)(ws + (size_t)48 * 1024 * 1024);
    __bf16* kbf  = (__bf16*)(ws + (size_t)56 * 1024 * 1024);
    __bf16* vtbf = (__bf16*)qbuf;   // qbuf dead after rope_rms_bf
    float*  obuf = kbuf;            // kbuf dead after rope_rms_bf

    const dim3 gemmBlk(256);
    const dim3 gemmGrd(D_ / 64, M_ / 64);

    gemm_f32<<<gemmGrd, gemmBlk, 0, stream>>>(x, Wq, qbuf, M_, D_, D_, D_, 0);
    gemm_f32<<<gemmGrd, gemmBlk, 0, stream>>>(x, Wk, kbuf, M_, D_, D_, D_, 0);
    gemm_f32<<<gemmGrd, gemmBlk, 0, stream>>>(x, Wv, vbuf, M_, D_, D_, D_, 0);

    rope_rms_bf<<<(B_ * N_ * H_) / 4, 256, 0, stream>>>(qbuf, kbuf, cs, sn, qbf, kbf);
    vconv<<<dim3(N_ / 64, B_ * H_), 256, 0, stream>>>(vbuf, vtbf);

    attn_mfma<<<dim3(N_ / 128, B_ * H_), 256, 0, stream>>>(qbf, kbf, vtbf, obuf);

    gemm_f32<<<gemmGrd, gemmBlk, 0, stream>>>(obuf, Woe, enc_out, M_, D_, D_, D_, 0);
    gemm_f32<<<gemmGrd, gemmBlk, 0, stream>>>(obuf, Wod, dec_out, M_, D_,
                                              (H_ - ENC_) * HD_, D_, ENC_ * HD_);
}

// Round 3
// 322.904 us; speedup vs baseline: 8.6437x; 2.2793x over previous
//
#include <hip/hip_runtime.h>
#include <hip/hip_bf16.h>
#include <math.h>

// Problem constants (fixed shapes from setup_inputs)
#define B_    2
#define N_    2048
#define D_    1024
#define H_    16
#define ENC_  8
#define HD_   64
#define EPS_  1e-5f
#define M_    (B_ * N_)        // 4096 rows for all GEMMs

typedef __bf16 bf16x8 __attribute__((ext_vector_type(8)));
typedef float  f32x4  __attribute__((ext_vector_type(4)));

#define MB(x) ((size_t)(x) * 1024 * 1024)

// Async global->LDS 16B copy. HW writes lds_base + lane*16; lds ptr must be
// wave-uniform and the lane->global mapping must match that contiguity.
__device__ __forceinline__ void gld16(const __bf16* g, __bf16* l) {
    __builtin_amdgcn_global_load_lds(
        (const __attribute__((address_space(1))) void*)g,
        (__attribute__((address_space(3))) void*)l,
        16, 0, 0);
}

// ---------------------------------------------------------------------------
// bf16 MFMA GEMM, B pre-transposed: C[M,Nn] = A[M,K] @ Bt[Nn,K]^T.
// m97 structure: 128x128 tile, BK=32, 4 waves (2x2), each wave 4x4 MFMA
// 16x16x32 tiles, global_load_lds width-16 staging, 2-barrier K-loop.
// A has row stride lda and column offset aoff (sliced dec projection).
// ---------------------------------------------------------------------------
template <typename OutT>
__global__ __launch_bounds__(256) void gemm_bt(
    const __bf16* __restrict__ A, const __bf16* __restrict__ Bt,
    OutT* __restrict__ C, int K, int lda, int aoff, int ldc)
{
    __shared__ __bf16 As[128 * 32];   // [row][k], 64 B rows
    __shared__ __bf16 Bs[128 * 32];   // [col][k]

    const int tid  = threadIdx.x;
    const int w    = tid >> 6;
    const int lane = tid & 63;
    const int lrow = lane & 15;
    const int quad = lane >> 4;
    const int wr   = w >> 1;           // wave row 0..1
    const int wc   = w & 1;            // wave col 0..1

    const int bm = blockIdx.y * 128;
    const int bn = blockIdx.x * 128;

    // Staging: batch t covers rows t*64 + w*16 + (lane>>2), k-chunk (lane&3)*8
    const int sr = lane >> 2;
    const int sc = (lane & 3) * 8;
    const __bf16* Ag0 = A  + (size_t)(bm +      w * 16 + sr) * lda + aoff + sc;
    const __bf16* Ag1 = A  + (size_t)(bm + 64 + w * 16 + sr) * lda + aoff + sc;
    const __bf16* Bg0 = Bt + (size_t)(bn +      w * 16 + sr) * K + sc;
    const __bf16* Bg1 = Bt + (size_t)(bn + 64 + w * 16 + sr) * K + sc;
    __bf16* Al0 = &As[w * 512];
    __bf16* Al1 = &As[2048 + w * 512];
    __bf16* Bl0 = &Bs[w * 512];
    __bf16* Bl1 = &Bs[2048 + w * 512];

    f32x4 acc[4][4];
    #pragma unroll
    for (int i = 0; i < 4; ++i)
        #pragma unroll
        for (int j = 0; j < 4; ++j) acc[i][j] = (f32x4){0.f, 0.f, 0.f, 0.f};

    for (int k0 = 0; k0 < K; k0 += 32) {
        gld16(Ag0 + k0, Al0);
        gld16(Ag1 + k0, Al1);
        gld16(Bg0 + k0, Bl0);
        gld16(Bg1 + k0, Bl1);
        __syncthreads();   // drains vmcnt -> LDS data visible

        bf16x8 af[4], bf[4];
        #pragma unroll
        for (int rt = 0; rt < 4; ++rt)
            af[rt] = *(const bf16x8*)&As[(wr * 64 + rt * 16 + lrow) * 32 + quad * 8];
        #pragma unroll
        for (int ct = 0; ct < 4; ++ct)
            bf[ct] = *(const bf16x8*)&Bs[(wc * 64 + ct * 16 + lrow) * 32 + quad * 8];

        #pragma unroll
        for (int rt = 0; rt < 4; ++rt)
            #pragma unroll
            for (int ct = 0; ct < 4; ++ct)
                acc[rt][ct] = __builtin_amdgcn_mfma_f32_16x16x32_bf16(
                    af[rt], bf[ct], acc[rt][ct], 0, 0, 0);
        __syncthreads();   // protect LDS from next iteration's staging
    }

    // C-layout: row = quad*4 + r (M), col = lrow (N)
    #pragma unroll
    for (int rt = 0; rt < 4; ++rt)
        #pragma unroll
        for (int ct = 0; ct < 4; ++ct)
            #pragma unroll
            for (int r = 0; r < 4; ++r) {
                const int row = bm + wr * 64 + rt * 16 + quad * 4 + r;
                const int col = bn + wc * 64 + ct * 16 + lrow;
                C[(size_t)row * ldc + col] = (OutT)acc[rt][ct][r];
            }
}

// ---------------------------------------------------------------------------
// fp32 -> bf16 straight convert (x). 8 elements / thread.
// ---------------------------------------------------------------------------
__global__ __launch_bounds__(256) void f32_to_bf16(
    const float* __restrict__ src, __bf16* __restrict__ dst)
{
    const size_t i = ((size_t)blockIdx.x * 256 + threadIdx.x) * 8;
    float4 a = *(const float4*)&src[i];
    float4 b = *(const float4*)&src[i + 4];
    bf16x8 o = {(__bf16)a.x, (__bf16)a.y, (__bf16)a.z, (__bf16)a.w,
                (__bf16)b.x, (__bf16)b.y, (__bf16)b.z, (__bf16)b.w};
    *(bf16x8*)&dst[i] = o;
}

// ---------------------------------------------------------------------------
// Weight convert + transpose: W[K,Nn] fp32 -> Wt[Nn,K] bf16. 64x64 LDS tiles.
// ---------------------------------------------------------------------------
__global__ __launch_bounds__(256) void wt_conv(
    const float* __restrict__ W, __bf16* __restrict__ Wt, int K, int Nn)
{
    __shared__ __bf16 t[64][72];
    const int kb = blockIdx.y * 64;
    const int nb = blockIdx.x * 64;
    {
        const int kl = threadIdx.x >> 2;
        const int c0 = (threadIdx.x & 3) * 16;
        const float* src = W + (size_t)(kb + kl) * Nn + nb + c0;
        #pragma unroll
        for (int u = 0; u < 4; ++u) {
            float4 f = *(const float4*)&src[u * 4];
            t[c0 + u * 4 + 0][kl] = (__bf16)f.x;
            t[c0 + u * 4 + 1][kl] = (__bf16)f.y;
            t[c0 + u * 4 + 2][kl] = (__bf16)f.z;
            t[c0 + u * 4 + 3][kl] = (__bf16)f.w;
        }
    }
    __syncthreads();
    {
        const int nl  = threadIdx.x >> 2;
        const int k0c = (threadIdx.x & 3) * 16;
        __bf16* dst = Wt + (size_t)(nb + nl) * K + kb + k0c;
        *(bf16x8*)&dst[0] = *(const bf16x8*)&t[nl][k0c];
        *(bf16x8*)&dst[8] = *(const bf16x8*)&t[nl][k0c + 8];
    }
}

// ---------------------------------------------------------------------------
// Fused RoPE + RMSNorm. Reads bf16 fused qkv [4096][3072] (q at col 0,
// k at col 1024), writes bf16 head-major (B,H,N,HD). One wave per row.
// ---------------------------------------------------------------------------
__global__ __launch_bounds__(256) void rope_rms_bf(
    const __bf16* __restrict__ qkv,
    const float* __restrict__ cs, const float* __restrict__ sn,
    __bf16* __restrict__ qbf, __bf16* __restrict__ kbf)
{
    const int row  = blockIdx.x * 4 + (threadIdx.x >> 6);  // (b*N + n)*H + h
    const int lane = threadIdx.x & 63;
    const int n    = (row >> 4) & (N_ - 1);
    const int b    = row >> 15;
    const int h    = row & 15;
    const int p    = lane >> 1;

    const float c = cs[n * (HD_ / 2) + p];
    const float s = sn[n * (HD_ / 2) + p];
    const size_t ibase = (size_t)(b * N_ + n) * 3072 + h * HD_ + lane;
    const size_t obase = ((size_t)(b * H_ + h) * N_ + n) * HD_ + lane;
    const bool odd = (lane & 1);

    {
        float val = (float)qkv[ibase];                  // q
        float partner = __shfl_xor(val, 1, 64);
        float r = odd ? fmaf(partner, s, val * c)
                      : (val * c - partner * s);
        float ss = r * r;
        #pragma unroll
        for (int off = 1; off < 64; off <<= 1) ss += __shfl_xor(ss, off, 64);
        qbf[obase] = (__bf16)(r * rsqrtf(ss * (1.0f / 64.0f) + EPS_));
    }
    {
        float val = (float)qkv[ibase + 1024];           // k
        float partner = __shfl_xor(val, 1, 64);
        float r = odd ? fmaf(partner, s, val * c)
                      : (val * c - partner * s);
        float ss = r * r;
        #pragma unroll
        for (int off = 1; off < 64; off <<= 1) ss += __shfl_xor(ss, off, 64);
        kbf[obase] = (__bf16)(r * rsqrtf(ss * (1.0f / 64.0f) + EPS_));
    }
}

// ---------------------------------------------------------------------------
// V transpose: bf16 v slice of qkv (cols 2048..3071) -> bf16 (B,H,HD,N).
// ---------------------------------------------------------------------------
__global__ __launch_bounds__(256) void vconv(
    const __bf16* __restrict__ qkv, __bf16* __restrict__ vt)
{
    __shared__ __bf16 tile[64][72];
    const int bh = blockIdx.y;
    const int b  = bh >> 4, h = bh & 15;
    const int n0 = blockIdx.x * 64;
    {
        const int nl = threadIdx.x >> 2;
        const int d0 = (threadIdx.x & 3) * 16;
        const __bf16* src = qkv + (size_t)(b * N_ + n0 + nl) * 3072 + 2048 + h * HD_ + d0;
        bf16x8 v0 = *(const bf16x8*)&src[0];
        bf16x8 v1 = *(const bf16x8*)&src[8];
        #pragma unroll
        for (int e = 0; e < 8; ++e) {
            tile[d0 + e][nl]     = v0[e];
            tile[d0 + 8 + e][nl] = v1[e];
        }
    }
    __syncthreads();
    {
        const int dl = threadIdx.x >> 2;
        const int nc = (threadIdx.x & 3) * 16;
        __bf16* dst = vt + ((size_t)(bh * HD_ + dl)) * N_ + n0 + nc;
        *(bf16x8*)&dst[0] = *(const bf16x8*)&tile[dl][nc];
        *(bf16x8*)&dst[8] = *(const bf16x8*)&tile[dl][nc + 8];
    }
}

// ---------------------------------------------------------------------------
// MFMA flash attention (bf16 in, bf16 out). Per wave: 32 query rows of one
// (b,h); 32-key tiles; fixed softmax max 8 (scores bounded by rms-norm+scale).
// P round-trips through LDS (C-layout -> A-layout); V pre-transposed.
// ---------------------------------------------------------------------------
__global__ __launch_bounds__(256) void attn_mfma(
    const __bf16* __restrict__ qbf, const __bf16* __restrict__ kbf,
    const __bf16* __restrict__ vtbf, __bf16* __restrict__ o)
{
    __shared__ __bf16 Plds[4][2][16][32];   // [wave][qtile][qrow][key]

    const int w    = threadIdx.x >> 6;
    const int lane = threadIdx.x & 63;
    const int lrow = lane & 15;
    const int quad = lane >> 4;

    const int bh = blockIdx.y;          // 0..31
    const int b  = bh >> 4, h = bh & 15;
    const bool enc = (h < ENC_);
    const int i0 = blockIdx.x * 128 + w * 32;

    const __bf16* qbase = qbf  + (size_t)bh * N_ * HD_;
    const __bf16* kbase = kbf  + (size_t)bh * N_ * HD_;
    const __bf16* vbase = vtbf + (size_t)bh * HD_ * N_;

    bf16x8 qf[2][2];
    #pragma unroll
    for (int qt = 0; qt < 2; ++qt)
        #pragma unroll
        for (int kc = 0; kc < 2; ++kc)
            qf[qt][kc] = *(const bf16x8*)
                &qbase[(size_t)(i0 + qt * 16 + lrow) * HD_ + kc * 32 + quad * 8];

    const f32x4 zero = {0.f, 0.f, 0.f, 0.f};
    f32x4 oacc[2][4];
    #pragma unroll
    for (int qt = 0; qt < 2; ++qt)
        #pragma unroll
        for (int c = 0; c < 4; ++c) oacc[qt][c] = zero;
    float lsum[2][4] = {};

    const float KS = 0.125f * 1.4426950408889634f;
    const float KO = -8.0f  * 1.4426950408889634f;

    const int jend = enc ? N_ : (i0 + 32);
    for (int j0 = 0; j0 < jend; j0 += 32) {
        bf16x8 kf0a = *(const bf16x8*)&kbase[(size_t)(j0 + lrow) * HD_ + quad * 8];
        bf16x8 kf0b = *(const bf16x8*)&kbase[(size_t)(j0 + lrow) * HD_ + 32 + quad * 8];
        bf16x8 kf1a = *(const bf16x8*)&kbase[(size_t)(j0 + 16 + lrow) * HD_ + quad * 8];
        bf16x8 kf1b = *(const bf16x8*)&kbase[(size_t)(j0 + 16 + lrow) * HD_ + 32 + quad * 8];

        #pragma unroll
        for (int qt = 0; qt < 2; ++qt) {
            f32x4 s0 = zero, s1 = zero;
            s0 = __builtin_amdgcn_mfma_f32_16x16x32_bf16(qf[qt][0], kf0a, s0, 0, 0, 0);
            s0 = __builtin_amdgcn_mfma_f32_16x16x32_bf16(qf[qt][1], kf0b, s0, 0, 0, 0);
            s1 = __builtin_amdgcn_mfma_f32_16x16x32_bf16(qf[qt][0], kf1a, s1, 0, 0, 0);
            s1 = __builtin_amdgcn_mfma_f32_16x16x32_bf16(qf[qt][1], kf1b, s1, 0, 0, 0);
            #pragma unroll
            for (int r = 0; r < 4; ++r) {
                const int i  = i0 + qt * 16 + quad * 4 + r;
                const int jA = j0 + lrow;
                const int jB = j0 + 16 + lrow;
                float pA = (enc || jA <= i) ? exp2f(fmaf(s0[r], KS, KO)) : 0.f;
                float pB = (enc || jB <= i) ? exp2f(fmaf(s1[r], KS, KO)) : 0.f;
                lsum[qt][r] += pA + pB;
                Plds[w][qt][quad * 4 + r][lrow]      = (__bf16)pA;
                Plds[w][qt][quad * 4 + r][lrow + 16] = (__bf16)pB;
            }
        }

        bf16x8 vf[4];
        #pragma unroll
        for (int c = 0; c < 4; ++c)
            vf[c] = *(const bf16x8*)&vbase[(size_t)(c * 16 + lrow) * N_ + j0 + quad * 8];

        #pragma unroll
        for (int qt = 0; qt < 2; ++qt) {
            bf16x8 pf = *(const bf16x8*)&Plds[w][qt][lrow][quad * 8];
            #pragma unroll
            for (int c = 0; c < 4; ++c)
                oacc[qt][c] = __builtin_amdgcn_mfma_f32_16x16x32_bf16(
                    pf, vf[c], oacc[qt][c], 0, 0, 0);
        }
    }

    #pragma unroll
    for (int qt = 0; qt < 2; ++qt)
        #pragma unroll
        for (int r = 0; r < 4; ++r) {
            float s = lsum[qt][r];
            s += __shfl_xor(s, 1, 64);
            s += __shfl_xor(s, 2, 64);
            s += __shfl_xor(s, 4, 64);
            s += __shfl_xor(s, 8, 64);
            lsum[qt][r] = 1.0f / s;
        }

    // O (bf16, [4096][1024], col = h*64 + dim)
    #pragma unroll
    for (int qt = 0; qt < 2; ++qt)
        #pragma unroll
        for (int c = 0; c < 4; ++c)
            #pragma unroll
            for (int r = 0; r < 4; ++r) {
                const int i = i0 + qt * 16 + quad * 4 + r;
                o[(size_t)(b * N_ + i) * D_ + h * HD_ + c * 16 + lrow] =
                    (__bf16)(oacc[qt][c][r] * lsum[qt][r]);
            }
}

// ---------------------------------------------------------------------------
extern "C" void kernel_launch(void* const* d_in, const int* in_sizes, int n_in,
                              void* d_out, int out_size, void* d_ws, size_t ws_size,
                              hipStream_t stream)
{
    const float* x   = (const float*)d_in[0];
    const float* cs  = (const float*)d_in[1];
    const float* sn  = (const float*)d_in[2];
    const float* Wq  = (const float*)d_in[3];
    const float* Wk  = (const float*)d_in[4];
    const float* Wv  = (const float*)d_in[5];
    const float* Woe = (const float*)d_in[6];
    const float* Wod = (const float*)d_in[7];

    float* enc_out = (float*)d_out;
    float* dec_out = enc_out + (size_t)M_ * D_;

    // Workspace (57 MB of >=64 MB), stream-ordered aliasing:
    //   [0,8)    xbf      -> reused as vtbf after QKV GEMM
    //   [8,14)   wqkv_t   (3072 x 1024 bf16: Wq^T | Wk^T | Wv^T)
    //   [14,16)  woe_t    (1024 x 1024 bf16)
    //   [16,17)  wod_t    (1024 x 512 bf16)
    //   [17,41)  qkv      (4096 x 3072 bf16) -> reused as obuf after rope/vconv
    //   [41,49)  qbf head-major (B,H,N,HD)
    //   [49,57)  kbf head-major
    char* ws = (char*)d_ws;
    __bf16* xbf    = (__bf16*)(ws);
    __bf16* wqkv_t = (__bf16*)(ws + MB(8));
    __bf16* woe_t  = (__bf16*)(ws + MB(14));
    __bf16* wod_t  = (__bf16*)(ws + MB(16));
    __bf16* qkv    = (__bf16*)(ws + MB(17));
    __bf16* qbf    = (__bf16*)(ws + MB(41));
    __bf16* kbf    = (__bf16*)(ws + MB(49));
    __bf16* vtbf   = xbf;     // xbf dead after QKV GEMM
    __bf16* obuf   = qkv;     // qkv dead after rope_rms_bf + vconv

    // Converts
    f32_to_bf16<<<(M_ * D_) / (256 * 8), 256, 0, stream>>>(x, xbf);
    wt_conv<<<dim3(16, 16), 256, 0, stream>>>(Wq, wqkv_t,                   D_, D_);
    wt_conv<<<dim3(16, 16), 256, 0, stream>>>(Wk, wqkv_t + 1024 * 1024,     D_, D_);
    wt_conv<<<dim3(16, 16), 256, 0, stream>>>(Wv, wqkv_t + 2 * 1024 * 1024, D_, D_);
    wt_conv<<<dim3(16, 16), 256, 0, stream>>>(Woe, woe_t, D_, D_);
    wt_conv<<<dim3(16, 8),  256, 0, stream>>>(Wod, wod_t, 512, D_);

    // Fused QKV projection (bf16 out)
    gemm_bt<__bf16><<<dim3(3072 / 128, M_ / 128), 256, 0, stream>>>(
        xbf, wqkv_t, qkv, D_, D_, 0, 3072);

    // RoPE + RMSNorm -> head-major bf16 q,k ; V transpose
    rope_rms_bf<<<(B_ * N_ * H_) / 4, 256, 0, stream>>>(qkv, cs, sn, qbf, kbf);
    vconv<<<dim3(N_ / 64, B_ * H_), 256, 0, stream>>>(qkv, vtbf);

    // Attention -> bf16 obuf [4096][1024]
    attn_mfma<<<dim3(N_ / 128, B_ * H_), 256, 0, stream>>>(qbf, kbf, vtbf, obuf);

    // Output projections (fp32 out)
    gemm_bt<float><<<dim3(D_ / 128, M_ / 128), 256, 0, stream>>>(
        obuf, woe_t, enc_out, D_, D_, 0, D_);
    gemm_bt<float><<<dim3(D_ / 128, M_ / 128), 256, 0, stream>>>(
        obuf, wod_t, dec_out, 512, D_, 512, D_);
}